// Round 8
// baseline (291.892 us; speedup 1.0000x reference)
//
#include <hip/hip_runtime.h>
#include <hip/hip_bf16.h>

typedef short short8 __attribute__((ext_vector_type(8)));
typedef float f32x4 __attribute__((ext_vector_type(4)));

#define M_TOT 16384   // B*S = 4*4096
#define NDIM  1024    // D = U = 1024
#define BK 32
#define NT (NDIM / BK)   // 32 K-tiles

static __device__ __forceinline__ unsigned short f2bf(float f) {
  unsigned int u = __builtin_bit_cast(unsigned int, f);
  unsigned int r = (u + 0x7fffu + ((u >> 16) & 1u)) >> 16;   // RN-even
  return (unsigned short)r;
}
static __device__ __forceinline__ float bf2f(unsigned short u) {
  return __builtin_bit_cast(float, ((unsigned int)u) << 16);
}

// compile-time-only reorder fence (zero runtime cost)
#define CLB() asm volatile("" ::: "memory")
#define VMW(N) asm volatile("s_waitcnt vmcnt(" #N ")" ::: "memory")
#define BAR() do { CLB(); __builtin_amdgcn_s_barrier(); CLB(); } while (0)

// ---------------- cast inputs fp32 -> bf16, vectorized ----------------
__global__ __launch_bounds__(256) void cast_in(const float* __restrict__ in,
                                               unsigned short* __restrict__ out,
                                               int n4) {
  int i = blockIdx.x * 256 + threadIdx.x;
  if (i >= n4) return;
  float4 v = reinterpret_cast<const float4*>(in)[i];
  ushort4 o;
  o.x = f2bf(v.x); o.y = f2bf(v.y); o.z = f2bf(v.z); o.w = f2bf(v.w);
  reinterpret_cast<ushort4*>(out)[i] = o;
}

// ---- transpose-cast 4 weights fp32 [K][N] -> bf16 [N][K], one launch ----
__global__ __launch_bounds__(256) void tcast4(
    const float* __restrict__ w1, const float* __restrict__ w2,
    const float* __restrict__ wg, const float* __restrict__ ws,
    unsigned short* __restrict__ W1t, unsigned short* __restrict__ W2t,
    unsigned short* __restrict__ Wgt, unsigned short* __restrict__ Wst) {
  const int z = blockIdx.z;
  const float* src = (z == 0) ? w1 : (z == 1) ? w2 : (z == 2) ? wg : ws;
  unsigned short* dst = (z == 0) ? W1t : (z == 1) ? W2t : (z == 2) ? Wgt : Wst;
  __shared__ unsigned short tile[32][33];
  int bx = blockIdx.x * 32, by = blockIdx.y * 32;
  int x = threadIdx.x & 31, y = threadIdx.x >> 5;  // 32 x 8
#pragma unroll
  for (int i = 0; i < 32; i += 8)
    tile[y + i][x] = f2bf(src[(size_t)(by + y + i) * NDIM + bx + x]);
  __syncthreads();
#pragma unroll
  for (int i = 0; i < 32; i += 8)
    dst[(size_t)(bx + y + i) * NDIM + by + x] = tile[x][y + i];
}

// ========== tri-GEMM: stage A once, multiply against 3 weights ==========
// H = bf16(relu(x@W1+b1)); G = bf16(sigmoid(x@Wg+bg)); S = bf16(x@Ws+bs)
// 128x128/weight, 4 waves, BK=32, 2 blocks/CU  (proven r6)
__global__ __launch_bounds__(256, 2) void trigemm(
    const unsigned short* __restrict__ A,
    const unsigned short* __restrict__ W1t,
    const unsigned short* __restrict__ Wgt,
    const unsigned short* __restrict__ Wst,
    const float* __restrict__ b1,
    const float* __restrict__ bg,
    const float* __restrict__ bs,
    unsigned short* __restrict__ H,
    unsigned short* __restrict__ G,
    unsigned short* __restrict__ S) {
  __shared__ __align__(16) unsigned short lds[2][4][128][BK];  // 64 KB

  const int tid = threadIdx.x;
  const int lane = tid & 63;
  const int wave = tid >> 6;            // 0..3
  const int wm = wave >> 1;             // 0..1
  const int wn = wave & 1;              // 0..1

  const int id = blockIdx.x;
  const int xcd = id & 7;
  const int slot = id >> 3;                // 0..127
  const int rblk = xcd + 8 * (slot >> 3);  // 0..127
  const int cblk = slot & 7;               // 0..7
  const int m0 = rblk * 128, n0 = cblk * 128;

  const unsigned short* gA = A + (size_t)m0 * NDIM;
  const unsigned short* gW[3] = {W1t + (size_t)n0 * NDIM, Wgt + (size_t)n0 * NDIM,
                                 Wst + (size_t)n0 * NDIM};

  f32x4 acc[3][4][4] = {};

  auto stage = [&](int buf, int kt) {
#pragma unroll
    for (int q = 0; q < 8; ++q) {
      const int mat = q >> 1;              // compile-time: 0=A,1..3=W
      int local = (q & 1) * 256 + tid;     // chunk within mat, 0..511
      int row = local >> 2;                // 0..127
      int c = (local & 3) ^ ((row >> 1) & 3);  // pre-swizzled global k-chunk
      const unsigned short* g =
          (mat == 0 ? gA : gW[mat - 1]) + (size_t)row * NDIM + kt * BK + c * 8;
      unsigned short* l = &lds[buf][0][0][0] +
                          (size_t)(q * 256 + (tid & ~63)) * 8;  // wave-uniform base
      __builtin_amdgcn_global_load_lds(
          (__attribute__((address_space(1))) void*)g,
          (__attribute__((address_space(3))) void*)l, 16, 0, 0);
    }
  };

  auto compute = [&](int buf) {
    short8 af[4];
#pragma unroll
    for (int mi = 0; mi < 4; ++mi) {
      int row = wm * 64 + mi * 16 + (lane & 15);
      int cs = (lane >> 4) ^ ((row >> 1) & 3);
      af[mi] = *reinterpret_cast<const short8*>(&lds[buf][0][row][cs * 8]);
    }
#pragma unroll
    for (int w = 0; w < 3; ++w) {
      short8 bf[4];
#pragma unroll
      for (int nj = 0; nj < 4; ++nj) {
        int row = wn * 64 + nj * 16 + (lane & 15);
        int cs = (lane >> 4) ^ ((row >> 1) & 3);
        bf[nj] = *reinterpret_cast<const short8*>(&lds[buf][1 + w][row][cs * 8]);
      }
      __builtin_amdgcn_s_setprio(1);
#pragma unroll
      for (int mi = 0; mi < 4; ++mi)
#pragma unroll
        for (int nj = 0; nj < 4; ++nj)
          acc[w][mi][nj] = __builtin_amdgcn_mfma_f32_16x16x32_bf16(
              af[mi], bf[nj], acc[w][mi][nj], 0, 0, 0);
      __builtin_amdgcn_s_setprio(0);
    }
  };

  stage(0, 0);
  for (int t = 0; t < NT; ++t) {
    const int cur = t & 1;
    if (t + 1 < NT) {
      stage(cur ^ 1, t + 1);
      VMW(8);
    } else {
      VMW(0);
    }
    BAR();
    compute(cur);
    BAR();
  }

  const int crow0 = m0 + wm * 64;
  const int ccol0 = n0 + wn * 64;
#pragma unroll
  for (int w = 0; w < 3; ++w) {
    const float* bptr = (w == 0) ? b1 : (w == 1) ? bg : bs;
    unsigned short* optr = (w == 0) ? H : (w == 1) ? G : S;
#pragma unroll
    for (int mi = 0; mi < 4; ++mi) {
#pragma unroll
      for (int nj = 0; nj < 4; ++nj) {
        int row = crow0 + mi * 16 + ((lane >> 4) << 2);
        int col = ccol0 + nj * 16 + (lane & 15);
        float bc = bptr[col];
#pragma unroll
        for (int r = 0; r < 4; ++r) {
          float v = acc[w][mi][nj][r] + bc;
          if (w == 0) v = fmaxf(v, 0.f);
          else if (w == 1) v = 1.f / (1.f + __expf(-v));
          optr[(size_t)(row + r) * NDIM + col] = f2bf(v);
        }
      }
    }
  }
}

// ====== fused GEMM-2 + gate + skip + LayerNorm, register-budgeted ======
// Out[m] = LN( (H@W2^T + b2) * G + S ) * gamma + beta   (fp32 out)
// Block = 32 rows x 1024 cols (full rows), 8 waves x 128 cols each.
// acc[2][8] = 64 VGPR; single-buffered frags (40 VGPR); launch_bounds
// (512,4) forces <=128 VGPR -> no scratch, 4 waves/SIMD for latency hiding.
// No LDS staging for fragments: W2 served by L2 (2 MB/XCD-resident),
// H k-slices by L1; each G/S/H byte read exactly once per block.
__global__ __launch_bounds__(512, 4) void gemm_y_ln(
    const unsigned short* __restrict__ H,
    const unsigned short* __restrict__ W2t,
    const float* __restrict__ b2,
    const unsigned short* __restrict__ G,
    const unsigned short* __restrict__ S,
    const float* __restrict__ gamma,
    const float* __restrict__ beta,
    float* __restrict__ Out) {
  const int tid = threadIdx.x;
  const int lane = tid & 63;
  const int wave = tid >> 6;        // 0..7 -> 128-col slice
  const int m0 = blockIdx.x * 32;
  const int c0 = wave * 128;
  const int lr = lane & 15;         // row (A) / col (B) within fragment
  const int lk = lane >> 4;         // k-chunk 0..3 (8 bf16 each)

  const unsigned short* aBase = H + (size_t)(m0 + lr) * NDIM + lk * 8;
  const unsigned short* bBase = W2t + (size_t)(c0 + lr) * NDIM + lk * 8;

  f32x4 acc[2][8] = {};

  for (int t = 0; t < NT; ++t) {
    short8 a[2], b[8];
#pragma unroll
    for (int mi = 0; mi < 2; ++mi)
      a[mi] = *reinterpret_cast<const short8*>(aBase + (size_t)mi * 16 * NDIM + t * BK);
#pragma unroll
    for (int nj = 0; nj < 8; ++nj)
      b[nj] = *reinterpret_cast<const short8*>(bBase + (size_t)nj * 16 * NDIM + t * BK);
#pragma unroll
    for (int mi = 0; mi < 2; ++mi)
#pragma unroll
      for (int nj = 0; nj < 8; ++nj)
        acc[mi][nj] = __builtin_amdgcn_mfma_f32_16x16x32_bf16(
            a[mi], b[nj], acc[mi][nj], 0, 0, 0);
  }

  // ---- epilogue: bias, gate, skip (fp32), per-row partial sums ----
  float s1[2][4], s2[2][4];
#pragma unroll
  for (int mi = 0; mi < 2; ++mi) {
#pragma unroll
    for (int r = 0; r < 4; ++r) {
      int row = m0 + mi * 16 + lk * 4 + r;
      float rs1 = 0.f, rs2 = 0.f;
#pragma unroll
      for (int nj = 0; nj < 8; ++nj) {
        int col = c0 + nj * 16 + lr;
        size_t idx = (size_t)row * NDIM + col;
        float v = acc[mi][nj][r] + b2[col];
        v = v * bf2f(G[idx]) + bf2f(S[idx]);
        acc[mi][nj][r] = v;
        rs1 += v; rs2 += v * v;
      }
      s1[mi][r] = rs1; s2[mi][r] = rs2;
    }
  }

  // reduce across the 16 lanes (lr) sharing the same rows
#pragma unroll
  for (int off = 1; off < 16; off <<= 1) {
#pragma unroll
    for (int mi = 0; mi < 2; ++mi)
#pragma unroll
      for (int r = 0; r < 4; ++r) {
        s1[mi][r] += __shfl_xor(s1[mi][r], off, 16);
        s2[mi][r] += __shfl_xor(s2[mi][r], off, 16);
      }
  }

  // cross-wave reduce via tiny LDS (rows 0..31)
  __shared__ float redS[8][32];
  __shared__ float redQ[8][32];
  __shared__ float2 fin[32];
  if (lr == 0) {
#pragma unroll
    for (int mi = 0; mi < 2; ++mi)
#pragma unroll
      for (int r = 0; r < 4; ++r) {
        int rl = mi * 16 + lk * 4 + r;
        redS[wave][rl] = s1[mi][r];
        redQ[wave][rl] = s2[mi][r];
      }
  }
  __syncthreads();
  if (tid < 32) {
    float a1 = 0.f, a2 = 0.f;
#pragma unroll
    for (int w = 0; w < 8; ++w) { a1 += redS[w][tid]; a2 += redQ[w][tid]; }
    float mu = a1 * (1.f / NDIM);
    float var = a2 * (1.f / NDIM) - mu * mu;
    fin[tid] = make_float2(mu, rsqrtf(var + 1e-3f));
  }
  __syncthreads();

  // normalize + write fp32 (gamma/beta loaded here, after s1/s2 die)
#pragma unroll
  for (int mi = 0; mi < 2; ++mi) {
#pragma unroll
    for (int r = 0; r < 4; ++r) {
      int rl = mi * 16 + lk * 4 + r;
      float2 f = fin[rl];
      float* orow = Out + (size_t)(m0 + rl) * NDIM;
#pragma unroll
      for (int nj = 0; nj < 8; ++nj) {
        int col = c0 + nj * 16 + lr;
        orow[col] = (acc[mi][nj][r] - f.x) * f.y * gamma[col] + beta[col];
      }
    }
  }
}

extern "C" void kernel_launch(void* const* d_in, const int* in_sizes, int n_in,
                              void* d_out, int out_size, void* d_ws, size_t ws_size,
                              hipStream_t stream) {
  const float* inp = (const float*)d_in[0];
  const float* w1 = (const float*)d_in[1];
  const float* b1 = (const float*)d_in[2];
  const float* w2 = (const float*)d_in[3];
  const float* b2 = (const float*)d_in[4];
  const float* wg = (const float*)d_in[5];
  const float* bg = (const float*)d_in[6];
  const float* wsk = (const float*)d_in[7];
  const float* bs = (const float*)d_in[8];
  const float* gamma = (const float*)d_in[9];
  const float* beta = (const float*)d_in[10];

  char* p = (char*)d_ws;
  const size_t act_bf16 = (size_t)M_TOT * NDIM * 2;
  const size_t w_bf16 = (size_t)NDIM * NDIM * 2;
  unsigned short* Ain = (unsigned short*)p; p += act_bf16;
  unsigned short* H   = (unsigned short*)p; p += act_bf16;
  unsigned short* G   = (unsigned short*)p; p += act_bf16;
  unsigned short* S   = (unsigned short*)p; p += act_bf16;
  unsigned short* W1t = (unsigned short*)p; p += w_bf16;
  unsigned short* W2t = (unsigned short*)p; p += w_bf16;
  unsigned short* Wgt = (unsigned short*)p; p += w_bf16;
  unsigned short* Wst = (unsigned short*)p; p += w_bf16;

  cast_in<<<(M_TOT * NDIM / 4 + 255) / 256, 256, 0, stream>>>(inp, Ain, M_TOT * NDIM / 4);
  tcast4<<<dim3(32, 32, 4), 256, 0, stream>>>(w1, w2, wg, wsk, W1t, W2t, Wgt, Wst);

  trigemm<<<(M_TOT / 128) * (NDIM / 128), 256, 0, stream>>>(
      Ain, W1t, Wgt, Wst, b1, bg, bs, H, G, S);
  gemm_y_ln<<<M_TOT / 32, 512, 0, stream>>>(H, W2t, b2, G, S, gamma, beta,
                                            (float*)d_out);
}

// Round 9
// 189.220 us; speedup vs baseline: 1.5426x; 1.5426x over previous
//
#include <hip/hip_runtime.h>
#include <hip/hip_bf16.h>

typedef short short8 __attribute__((ext_vector_type(8)));
typedef float f32x4 __attribute__((ext_vector_type(4)));

#define M_TOT 16384   // B*S = 4*4096
#define NDIM  1024    // D = U = 1024
#define BK 32
#define NT (NDIM / BK)   // 32 K-tiles

static __device__ __forceinline__ unsigned short f2bf(float f) {
  unsigned int u = __builtin_bit_cast(unsigned int, f);
  unsigned int r = (u + 0x7fffu + ((u >> 16) & 1u)) >> 16;   // RN-even
  return (unsigned short)r;
}
static __device__ __forceinline__ float bf2f(unsigned short u) {
  return __builtin_bit_cast(float, ((unsigned int)u) << 16);
}

// compile-time-only reorder fence (zero runtime cost)
#define CLB() asm volatile("" ::: "memory")
#define VMW(N) asm volatile("s_waitcnt vmcnt(" #N ")" ::: "memory")
#define BAR() do { CLB(); __builtin_amdgcn_s_barrier(); CLB(); } while (0)

// ---------------- cast inputs fp32 -> bf16, vectorized ----------------
__global__ __launch_bounds__(256) void cast_in(const float* __restrict__ in,
                                               unsigned short* __restrict__ out,
                                               int n4) {
  int i = blockIdx.x * 256 + threadIdx.x;
  if (i >= n4) return;
  float4 v = reinterpret_cast<const float4*>(in)[i];
  ushort4 o;
  o.x = f2bf(v.x); o.y = f2bf(v.y); o.z = f2bf(v.z); o.w = f2bf(v.w);
  reinterpret_cast<ushort4*>(out)[i] = o;
}

// ---- transpose-cast 4 weights fp32 [K][N] -> bf16 [N][K], one launch ----
__global__ __launch_bounds__(256) void tcast4(
    const float* __restrict__ w1, const float* __restrict__ w2,
    const float* __restrict__ wg, const float* __restrict__ ws,
    unsigned short* __restrict__ W1t, unsigned short* __restrict__ W2t,
    unsigned short* __restrict__ Wgt, unsigned short* __restrict__ Wst) {
  const int z = blockIdx.z;
  const float* src = (z == 0) ? w1 : (z == 1) ? w2 : (z == 2) ? wg : ws;
  unsigned short* dst = (z == 0) ? W1t : (z == 1) ? W2t : (z == 2) ? Wgt : Wst;
  __shared__ unsigned short tile[32][33];
  int bx = blockIdx.x * 32, by = blockIdx.y * 32;
  int x = threadIdx.x & 31, y = threadIdx.x >> 5;  // 32 x 8
#pragma unroll
  for (int i = 0; i < 32; i += 8)
    tile[y + i][x] = f2bf(src[(size_t)(by + y + i) * NDIM + bx + x]);
  __syncthreads();
#pragma unroll
  for (int i = 0; i < 32; i += 8)
    dst[(size_t)(bx + y + i) * NDIM + by + x] = tile[x][y + i];
}

// ========== tri-GEMM v2: 256x128 tile, 8 waves, stage A once ==========
// H = bf16(relu(x@W1+b1)); G = bf16(sigmoid(x@Wg+bg)); S = bf16(x@Ws+bs)
// Per block: 256 rows x 128 cols per weight; 8 waves (4x2), per wave
// 64x64 per weight (acc 3x4x4 f32x4 = 192 regs, proven r6).  LDS per buf:
// A 256x32 (16KB) + 3x W 128x32 (24KB) = 40KB; x2 buf = 80KB -> exactly
// 2 blocks/CU = 16 waves/CU (4/SIMD, 2x the TLP of r6's 128x128).
// B-staging bytes per FLOP halved vs r6 (24KB W per 6.3 MFLOP).
// Same proven swizzle (cs ^ (row>>1)&3, 0 conflicts) and counted-vmcnt
// 2-barrier loop; 5 loads/thread/tile -> VMW(5).
__global__ __launch_bounds__(512, 2) void trigemm(
    const unsigned short* __restrict__ A,
    const unsigned short* __restrict__ W1t,
    const unsigned short* __restrict__ Wgt,
    const unsigned short* __restrict__ Wst,
    const float* __restrict__ b1,
    const float* __restrict__ bg,
    const float* __restrict__ bs,
    unsigned short* __restrict__ H,
    unsigned short* __restrict__ G,
    unsigned short* __restrict__ S) {
  // per buf: shorts 0..8191 = A (row-major 256x32), 8192 + w*4096 + row*32 = W_w
  __shared__ __align__(16) unsigned short lds[2][20480];  // 80 KB

  const int tid = threadIdx.x;
  const int lane = tid & 63;
  const int wave = tid >> 6;            // 0..7
  const int wm = wave >> 1;             // 0..3  (64-row band)
  const int wn = wave & 1;              // 0..1  (64-col half)
  const int lr = lane & 15;
  const int lk = lane >> 4;

  // XCD swizzle: 8 col-blocks sharing an A row-panel -> same XCD.
  // Bijective over 512 blocks.
  const int id = blockIdx.x;
  const int xcd = id & 7;
  const int slot = id >> 3;                // 0..63
  const int rblk = xcd + 8 * (slot >> 3);  // 0..63
  const int cblk = slot & 7;               // 0..7
  const int m0 = rblk * 256, n0 = cblk * 128;

  const unsigned short* gA = A + (size_t)m0 * NDIM;
  const unsigned short* gW[3] = {W1t + (size_t)n0 * NDIM, Wgt + (size_t)n0 * NDIM,
                                 Wst + (size_t)n0 * NDIM};

  f32x4 acc[3][4][4] = {};

  // stage K-tile kt: A 1024 chunks + 3x512 W chunks = 2560 / 512thr = 5 each
  auto stage = [&](int buf, int kt) {
#pragma unroll
    for (int q = 0; q < 5; ++q) {
      int cid = q * 512 + tid;             // 0..2559
      const unsigned short* g;
      if (q < 2) {                          // A chunks 0..1023
        int row = cid >> 2;                 // 0..255
        int c = (cid & 3) ^ ((row >> 1) & 3);
        g = gA + (size_t)row * NDIM + kt * BK + c * 8;
      } else {                              // W chunks, mat = q-2 (compile-time)
        int local = cid - 1024 - (q - 2) * 512 + (q - 2) * 512;  // = cid-1024
        local = cid - 1024;
        int w = q - 2;
        int lrow = local & 511;
        int row = lrow >> 2;                // 0..127
        int c = (lrow & 3) ^ ((row >> 1) & 3);
        g = gW[w] + (size_t)row * NDIM + kt * BK + c * 8;
      }
      unsigned short* l = &lds[buf][0] + (size_t)(q * 512 + (tid & ~63)) * 8;
      __builtin_amdgcn_global_load_lds(
          (__attribute__((address_space(1))) void*)g,
          (__attribute__((address_space(3))) void*)l, 16, 0, 0);
    }
  };

  auto compute = [&](int buf) {
    short8 af[4];
#pragma unroll
    for (int mi = 0; mi < 4; ++mi) {
      int row = wm * 64 + mi * 16 + lr;
      int cs = lk ^ ((row >> 1) & 3);
      af[mi] = *reinterpret_cast<const short8*>(&lds[buf][row * 32 + cs * 8]);
    }
#pragma unroll
    for (int w = 0; w < 3; ++w) {
      short8 bf[4];
#pragma unroll
      for (int nj = 0; nj < 4; ++nj) {
        int row = wn * 64 + nj * 16 + lr;
        int cs = lk ^ ((row >> 1) & 3);
        bf[nj] = *reinterpret_cast<const short8*>(
            &lds[buf][8192 + w * 4096 + row * 32 + cs * 8]);
      }
      __builtin_amdgcn_s_setprio(1);
#pragma unroll
      for (int mi = 0; mi < 4; ++mi)
#pragma unroll
        for (int nj = 0; nj < 4; ++nj)
          acc[w][mi][nj] = __builtin_amdgcn_mfma_f32_16x16x32_bf16(
              af[mi], bf[nj], acc[w][mi][nj], 0, 0, 0);
      __builtin_amdgcn_s_setprio(0);
    }
  };

  stage(0, 0);
  for (int t = 0; t < NT; ++t) {
    const int cur = t & 1;
    if (t + 1 < NT) {
      stage(cur ^ 1, t + 1);   // 5 new in flight, then wait current 5
      VMW(5);
    } else {
      VMW(0);
    }
    BAR();
    compute(cur);
    BAR();
  }

  // epilogue: C/D layout col = lane&15, row = (lane>>4)*4 + r
  const int crow0 = m0 + wm * 64;
  const int ccol0 = n0 + wn * 64;
#pragma unroll
  for (int w = 0; w < 3; ++w) {
    const float* bptr = (w == 0) ? b1 : (w == 1) ? bg : bs;
    unsigned short* optr = (w == 0) ? H : (w == 1) ? G : S;
#pragma unroll
    for (int mi = 0; mi < 4; ++mi) {
#pragma unroll
      for (int nj = 0; nj < 4; ++nj) {
        int row = crow0 + mi * 16 + (lk << 2);
        int col = ccol0 + nj * 16 + lr;
        float bc = bptr[col];
#pragma unroll
        for (int r = 0; r < 4; ++r) {
          float v = acc[w][mi][nj][r] + bc;
          if (w == 0) v = fmaxf(v, 0.f);
          else if (w == 1) v = 1.f / (1.f + __expf(-v));
          optr[(size_t)(row + r) * NDIM + col] = f2bf(v);
        }
      }
    }
  }
}

// ========== 256x256 / BK=32, 8-wave, 4-slot LDS ring: y-GEMM ==========
// O = bf16((H@W2t^T + b2) * G + S)    (proven r5/r6)
__global__ __launch_bounds__(512, 2) void gemm_y(
    const unsigned short* __restrict__ A,
    const unsigned short* __restrict__ Bt,
    const float* __restrict__ bias,
    unsigned short* __restrict__ O,
    const unsigned short* __restrict__ G,
    const unsigned short* __restrict__ S) {
  __shared__ __align__(16) unsigned short lds[4][2][256][BK];  // 128 KB

  const int tid = threadIdx.x;
  const int lane = tid & 63;
  const int wave = tid >> 6;            // 0..7
  const int wm = wave >> 2;             // 0..1
  const int wn = wave & 3;              // 0..3

  const int id = blockIdx.x;
  const int xcd = id & 7;
  const int slot0 = id >> 3;               // 0..31
  const int rblk = xcd + 8 * (slot0 >> 2); // 0..63
  const int cblk = slot0 & 3;              // 0..3
  const int m0 = rblk * 256, n0 = cblk * 256;

  const unsigned short* gA = A + (size_t)m0 * NDIM;
  const unsigned short* gB = Bt + (size_t)n0 * NDIM;

  f32x4 acc[8][4] = {};

  auto stage = [&](int slot, int kt) {
#pragma unroll
    for (int q = 0; q < 4; ++q) {
      int cid = q * 512 + tid;
      int mat = q >> 1;
      int local = cid & 1023;
      int row = local >> 2;
      int c = (local & 3) ^ ((row >> 1) & 3);
      const unsigned short* g =
          (mat ? gB : gA) + (size_t)row * NDIM + kt * BK + c * 8;
      unsigned short* l = &lds[slot][mat][0][0] +
                          (size_t)((q * 512 + (tid & ~63)) & 1023) * 8;
      __builtin_amdgcn_global_load_lds(
          (__attribute__((address_space(1))) void*)g,
          (__attribute__((address_space(3))) void*)l, 16, 0, 0);
    }
  };

  auto compute = [&](int slot) {
    short8 af[8], bf[4];
#pragma unroll
    for (int nj = 0; nj < 4; ++nj) {
      int row = wn * 64 + nj * 16 + (lane & 15);
      int cs = (lane >> 4) ^ ((row >> 1) & 3);
      bf[nj] = *reinterpret_cast<const short8*>(&lds[slot][1][row][cs * 8]);
    }
#pragma unroll
    for (int mi = 0; mi < 8; ++mi) {
      int row = wm * 128 + mi * 16 + (lane & 15);
      int cs = (lane >> 4) ^ ((row >> 1) & 3);
      af[mi] = *reinterpret_cast<const short8*>(&lds[slot][0][row][cs * 8]);
    }
    __builtin_amdgcn_s_setprio(1);
#pragma unroll
    for (int mi = 0; mi < 8; ++mi)
#pragma unroll
      for (int nj = 0; nj < 4; ++nj)
        acc[mi][nj] = __builtin_amdgcn_mfma_f32_16x16x32_bf16(
            af[mi], bf[nj], acc[mi][nj], 0, 0, 0);
    __builtin_amdgcn_s_setprio(0);
  };

  stage(0, 0);
  stage(1, 1);
  stage(2, 2);
  VMW(8);
  BAR();

#pragma unroll 4
  for (int t = 0; t < NT - 4; ++t) {
    stage((t + 3) & 3, t + 3);
    compute(t & 3);
    VMW(8);
    BAR();
  }
  stage(3, 31);
  compute(0);
  VMW(8);
  BAR();
  compute(1);
  VMW(4);
  BAR();
  compute(2);
  VMW(0);
  BAR();
  compute(3);

  const int crow0 = m0 + wm * 128;
  const int ccol0 = n0 + wn * 64;
#pragma unroll
  for (int mi = 0; mi < 8; ++mi) {
#pragma unroll
    for (int nj = 0; nj < 4; ++nj) {
      int row = crow0 + mi * 16 + ((lane >> 4) << 2);
      int col = ccol0 + nj * 16 + (lane & 15);
      float bc = bias[col];
#pragma unroll
      for (int r = 0; r < 4; ++r) {
        float v = acc[mi][nj][r] + bc;
        size_t idx = (size_t)(row + r) * NDIM + col;
        O[idx] = f2bf(v * bf2f(G[idx]) + bf2f(S[idx]));
      }
    }
  }
}

// -------- LayerNorm: bf16 rows in, fp32 out --------
__global__ __launch_bounds__(256) void layernorm_bf(
    const unsigned short* __restrict__ Ybf, float* __restrict__ Out,
    const float* __restrict__ gamma, const float* __restrict__ beta) {
  const int tid = threadIdx.x;
  const unsigned short* y = Ybf + (size_t)blockIdx.x * NDIM;
  ushort4 u = reinterpret_cast<const ushort4*>(y)[tid];
  float v0 = bf2f(u.x), v1 = bf2f(u.y), v2 = bf2f(u.z), v3 = bf2f(u.w);
  float s1 = v0 + v1 + v2 + v3;
  float s2 = v0 * v0 + v1 * v1 + v2 * v2 + v3 * v3;
#pragma unroll
  for (int o = 32; o > 0; o >>= 1) {
    s1 += __shfl_down(s1, o, 64);
    s2 += __shfl_down(s2, o, 64);
  }
  __shared__ float red[8];
  int wave = tid >> 6, lane = tid & 63;
  if (lane == 0) { red[wave] = s1; red[wave + 4] = s2; }
  __syncthreads();
  float S1 = red[0] + red[1] + red[2] + red[3];
  float S2 = red[4] + red[5] + red[6] + red[7];
  float mu = S1 * (1.f / NDIM);
  float var = S2 * (1.f / NDIM) - mu * mu;
  float inv = rsqrtf(var + 1e-3f);
  float4 gm = reinterpret_cast<const float4*>(gamma)[tid];
  float4 bt = reinterpret_cast<const float4*>(beta)[tid];
  float4 o;
  o.x = (v0 - mu) * inv * gm.x + bt.x;
  o.y = (v1 - mu) * inv * gm.y + bt.y;
  o.z = (v2 - mu) * inv * gm.z + bt.z;
  o.w = (v3 - mu) * inv * gm.w + bt.w;
  reinterpret_cast<float4*>(Out + (size_t)blockIdx.x * NDIM)[tid] = o;
}

extern "C" void kernel_launch(void* const* d_in, const int* in_sizes, int n_in,
                              void* d_out, int out_size, void* d_ws, size_t ws_size,
                              hipStream_t stream) {
  const float* inp = (const float*)d_in[0];
  const float* w1 = (const float*)d_in[1];
  const float* b1 = (const float*)d_in[2];
  const float* w2 = (const float*)d_in[3];
  const float* b2 = (const float*)d_in[4];
  const float* wg = (const float*)d_in[5];
  const float* bg = (const float*)d_in[6];
  const float* wsk = (const float*)d_in[7];
  const float* bs = (const float*)d_in[8];
  const float* gamma = (const float*)d_in[9];
  const float* beta = (const float*)d_in[10];

  char* p = (char*)d_ws;
  const size_t act_bf16 = (size_t)M_TOT * NDIM * 2;
  const size_t w_bf16 = (size_t)NDIM * NDIM * 2;
  unsigned short* Ain = (unsigned short*)p; p += act_bf16;
  unsigned short* H   = (unsigned short*)p; p += act_bf16;
  unsigned short* G   = (unsigned short*)p; p += act_bf16;
  unsigned short* S   = (unsigned short*)p; p += act_bf16;
  unsigned short* Ybf = (unsigned short*)p; p += act_bf16;
  unsigned short* W1t = (unsigned short*)p; p += w_bf16;
  unsigned short* W2t = (unsigned short*)p; p += w_bf16;
  unsigned short* Wgt = (unsigned short*)p; p += w_bf16;
  unsigned short* Wst = (unsigned short*)p; p += w_bf16;

  cast_in<<<(M_TOT * NDIM / 4 + 255) / 256, 256, 0, stream>>>(inp, Ain, M_TOT * NDIM / 4);
  tcast4<<<dim3(32, 32, 4), 256, 0, stream>>>(w1, w2, wg, wsk, W1t, W2t, Wgt, Wst);

  trigemm<<<(M_TOT / 256) * (NDIM / 128), 512, 0, stream>>>(
      Ain, W1t, Wgt, Wst, b1, bg, bs, H, G, S);
  gemm_y<<<(M_TOT / 256) * (NDIM / 256), 512, 0, stream>>>(H, W2t, b2, Ybf, G, S);
  layernorm_bf<<<M_TOT, 256, 0, stream>>>(Ybf, (float*)d_out, gamma, beta);
}